// Round 2
// baseline (813.388 us; speedup 1.0000x reference)
//
#include <hip/hip_runtime.h>
#include <hip/hip_bf16.h>

// Shapes (fixed for this problem)
constexpr int B = 2, N = 512, H = 12, C = 16, PQ = 4, PV = 8, CZ = 128, CS = 384;
constexpr int HC   = H * C;            // 192
constexpr int KVCOLS = 2 * HC;         // 384
constexpr int QPCOLS = 3 * PQ * H;     // 144
constexpr int KVPCOLS = 3 * (PQ + PV) * H; // 432
constexpr int QP3 = H * PQ * 3;        // 144 (layout [h][pq][x])
constexpr int VP3 = H * PV * 3;        // 288 (layout [h][pv][x])
constexpr int FEAT = (CZ + C + PV * 4) * H; // 2112
constexpr float QK_SCALE  = 0.14433756729740643f;  // (3*C)^-0.5
constexpr float INV_SQRT3 = 0.5773502691896258f;
constexpr float WC_IS3    = 0.13608276348795434f;  // sqrt(2/(9*PQ))*3^-0.5 = sqrt(1/54)

// ---------------------------------------------------------------------------
// Kernel 1: projections q,k,v (s@W) and rotated point projections qp,kp,vp
// One block per (b,i) row. 1024 blocks x 256 threads.
// ---------------------------------------------------------------------------
__global__ __launch_bounds__(256) void k_proj(
    const float* __restrict__ s, const float* __restrict__ rot, const float* __restrict__ trans,
    const float* __restrict__ Wq, const float* __restrict__ bq,
    const float* __restrict__ Wkv, const float* __restrict__ bkv,
    const float* __restrict__ Wqp, const float* __restrict__ bqp,
    const float* __restrict__ Wkvp, const float* __restrict__ bkvp,
    float* __restrict__ qw, float* __restrict__ kw, float* __restrict__ vw,
    float* __restrict__ qpw, float* __restrict__ kpw, float* __restrict__ vpw)
{
    __shared__ float s_s[CS];
    __shared__ float rawqp[QPCOLS];
    __shared__ float rawkvp[KVPCOLS];
    __shared__ float R[9], T[3];
    const int t = threadIdx.x;
    const int bi = blockIdx.x;

    const float* srow = s + (size_t)bi * CS;
    if (t < CS / 4) ((float4*)s_s)[t] = ((const float4*)srow)[t];
    if (t < 9) R[t] = rot[bi * 9 + t];
    if (t < 3) T[t] = trans[bi * 3 + t];
    __syncthreads();

    // q = s @ Wq + bq   (192 cols)
    if (t < HC) {
        float acc = bq[t];
        #pragma unroll 4
        for (int k = 0; k < CS; ++k) acc += s_s[k] * Wq[k * HC + t];
        qw[(size_t)bi * HC + t] = acc;
    }
    // kv = s @ Wkv + bkv (384 cols) -> split k / v per head
    for (int col = t; col < KVCOLS; col += 256) {
        float acc = bkv[col];
        #pragma unroll 4
        for (int k = 0; k < CS; ++k) acc += s_s[k] * Wkv[k * KVCOLS + col];
        int h = col >> 5, cc = col & 31;
        if (cc < C) kw[(size_t)bi * HC + h * C + cc] = acc;
        else        vw[(size_t)bi * HC + h * C + (cc - C)] = acc;
    }
    // qp raw (144 cols): chunk y is cols [y*48,(y+1)*48)
    if (t < QPCOLS) {
        float acc = bqp[t];
        #pragma unroll 4
        for (int k = 0; k < CS; ++k) acc += s_s[k] * Wqp[k * QPCOLS + t];
        rawqp[t] = acc;
    }
    // kvp raw (432 cols): chunk y is cols [y*144,(y+1)*144)
    for (int col = t; col < KVPCOLS; col += 256) {
        float acc = bkvp[col];
        #pragma unroll 4
        for (int k = 0; k < CS; ++k) acc += s_s[k] * Wkvp[k * KVPCOLS + col];
        rawkvp[col] = acc;
    }
    __syncthreads();

    // rotate qp: out[x] = T[x] + sum_y R[x][y]*raw[y*48+p], p = h*4+pq
    if (t < 48) {
        int p = t, h = p >> 2, pq = p & 3;
        float y0 = rawqp[0 * 48 + p], y1 = rawqp[1 * 48 + p], y2 = rawqp[2 * 48 + p];
        #pragma unroll
        for (int x = 0; x < 3; ++x) {
            float v = T[x] + R[x * 3 + 0] * y0 + R[x * 3 + 1] * y1 + R[x * 3 + 2] * y2;
            qpw[(size_t)bi * QP3 + h * 12 + pq * 3 + x] = v;
        }
    }
    // rotate kvp: p = h*12+pp; pp<4 -> kp else vp
    if (t < 144) {
        int p = t, h = p / 12, pp = p % 12;
        float y0 = rawkvp[0 * 144 + p], y1 = rawkvp[1 * 144 + p], y2 = rawkvp[2 * 144 + p];
        #pragma unroll
        for (int x = 0; x < 3; ++x) {
            float v = T[x] + R[x * 3 + 0] * y0 + R[x * 3 + 1] * y1 + R[x * 3 + 2] * y2;
            if (pp < PQ) kpw[(size_t)bi * QP3 + h * 12 + pp * 3 + x] = v;
            else         vpw[(size_t)bi * VP3 + h * 24 + (pp - PQ) * 3 + x] = v;
        }
    }
}

// ---------------------------------------------------------------------------
// Kernel 2: fused attention with online softmax — single pass over z.
// One block per (b,i). Chunks of J=16 keys. LDS ~38KB -> 4 blocks/CU.
// ---------------------------------------------------------------------------
constexpr int J = 16;

__global__ __launch_bounds__(256) void k_attn(
    const float* __restrict__ z, const float* __restrict__ rot, const float* __restrict__ trans,
    const float* __restrict__ seq_mask,
    const float* __restrict__ Wb, const float* __restrict__ bb, const float* __restrict__ gamma,
    const float* __restrict__ qw, const float* __restrict__ kw, const float* __restrict__ vw,
    const float* __restrict__ qpw, const float* __restrict__ kpw, const float* __restrict__ vpw,
    float* __restrict__ feat)
{
    __shared__ float z_s[J * 129];     // +1 pad: logit phase lanes vary j
    __shared__ float k_s[J * 193];
    __shared__ float kp_s[J * 145];
    __shared__ float logit_s[H * 17];
    __shared__ float q_s[HC], qp_s[QP3];
    __shared__ float Wb_s[CZ * H];
    __shared__ float bb_s[H], pac_s[H], m_s[H], l_s[H], sc_s[H];
    __shared__ float R[9], T[3], mask_s[J];

    const int t = threadIdx.x;
    const int bi = blockIdx.x;
    const int b = bi >> 9;           // N = 512
    const int i = bi & (N - 1);

    if (t < HC)  q_s[t]  = qw[(size_t)bi * HC + t];
    if (t < QP3) qp_s[t] = qpw[(size_t)bi * QP3 + t];
    for (int idx = t; idx < CZ * H; idx += 256) Wb_s[idx] = Wb[idx];
    if (t < H) {
        bb_s[t] = bb[t];
        float g = gamma[t];
        float sp = fmaxf(g, 0.0f) + log1pf(expf(-fabsf(g)));   // stable softplus
        pac_s[t] = -0.5f * sp * WC_IS3;
        m_s[t] = -INFINITY;
        l_s[t] = 0.0f;
    }
    if (t < 9) R[t] = rot[bi * 9 + t];
    if (t < 3) T[t] = trans[bi * 3 + t];
    const float mask_i = seq_mask[bi];

    float accP[6] = {0, 0, 0, 0, 0, 0};   // opair: flat = t+256r -> h=flat>>7, c=flat&127
    float accO = 0.0f;                    // o: t<192 -> h=t>>4, c=t&15
    float accV0 = 0, accV1 = 0, accV2 = 0; // op: t<96 -> h=t>>3, p=t&7

    const float* zrow = z + ((size_t)b * N + i) * N * CZ;

    for (int j0 = 0; j0 < N; j0 += J) {
        __syncthreads();   // previous accumulate done reading LDS
        // ---- stage z, k, kp, mask ----
        for (int q4 = t; q4 < J * CZ / 4; q4 += 256) {
            int j = q4 >> 5, c4 = q4 & 31;
            float4 val = ((const float4*)(zrow + (size_t)(j0 + j) * CZ))[c4];
            float* d = &z_s[j * 129 + c4 * 4];
            d[0] = val.x; d[1] = val.y; d[2] = val.z; d[3] = val.w;
        }
        for (int q4 = t; q4 < J * HC / 4; q4 += 256) {
            int j = q4 / 48, c4 = q4 % 48;
            float4 val = ((const float4*)(kw + (size_t)(b * N + j0 + j) * HC))[c4];
            float* d = &k_s[j * 193 + c4 * 4];
            d[0] = val.x; d[1] = val.y; d[2] = val.z; d[3] = val.w;
        }
        for (int q4 = t; q4 < J * QP3 / 4; q4 += 256) {
            int j = q4 / 36, c4 = q4 % 36;
            float4 val = ((const float4*)(kpw + (size_t)(b * N + j0 + j) * QP3))[c4];
            float* d = &kp_s[j * 145 + c4 * 4];
            d[0] = val.x; d[1] = val.y; d[2] = val.z; d[3] = val.w;
        }
        if (t < J) mask_s[t] = seq_mask[b * N + j0 + t];
        __syncthreads();

        // ---- logits: 192 threads, (h = t>>4, j = t&15) ----
        if (t < H * J) {
            int j = t & (J - 1), h = t >> 4;
            float bp = bb_s[h];
            #pragma unroll 8
            for (int c = 0; c < CZ; ++c) bp += z_s[j * 129 + c] * Wb_s[c * H + h];
            float qk = 0.0f;
            #pragma unroll
            for (int c = 0; c < C; ++c) qk += q_s[h * C + c] * k_s[j * 193 + h * C + c];
            float d2 = 0.0f;
            #pragma unroll
            for (int e = 0; e < 12; ++e) {
                float d = qp_s[h * 12 + e] - kp_s[j * 145 + h * 12 + e];
                d2 += d * d;
            }
            logit_s[h * 17 + j] = QK_SCALE * qk + INV_SQRT3 * bp + pac_s[h] * d2
                                + 100000.0f * (mask_i * mask_s[j] - 1.0f);
        }
        __syncthreads();
        // ---- chunk max + rescale factor (12 threads, 16 iters, no exp) ----
        if (t < H) {
            float cm = -INFINITY;
            for (int j = 0; j < J; ++j) cm = fmaxf(cm, logit_s[t * 17 + j]);
            float mnew = fmaxf(m_s[t], cm);
            sc_s[t] = expf(m_s[t] - mnew);   // exp(-inf)=0 on first chunk
            m_s[t] = mnew;
        }
        __syncthreads();
        // ---- exp in parallel (192 threads) ----
        if (t < H * J) {
            int j = t & (J - 1), h = t >> 4;
            logit_s[h * 17 + j] = expf(logit_s[h * 17 + j] - m_s[h]);
        }
        __syncthreads();
        if (t < H) {
            float ssum = 0.0f;
            for (int j = 0; j < J; ++j) ssum += logit_s[t * 17 + j];
            l_s[t] = l_s[t] * sc_s[t] + ssum;
        }
        __syncthreads();

        // ---- accumulate ----
        #pragma unroll
        for (int r = 0; r < 6; ++r) {        // opair
            int flat = t + 256 * r;
            int h = flat >> 7, c = flat & 127;
            float a = accP[r] * sc_s[h];
            #pragma unroll 4
            for (int j = 0; j < J; ++j) a += logit_s[h * 17 + j] * z_s[j * 129 + c];
            accP[r] = a;
        }
        if (t < HC) {                        // o (v from global, L2-resident)
            int h = t >> 4;
            const float* vb = vw + (size_t)(b * N + j0) * HC + t;
            float a = accO * sc_s[h];
            #pragma unroll 4
            for (int j = 0; j < J; ++j) a += logit_s[h * 17 + j] * vb[(size_t)j * HC];
            accO = a;
        }
        if (t < H * PV) {                    // op (vp from global, L2-resident)
            int h = t >> 3;
            const float* vpb = vpw + (size_t)(b * N + j0) * VP3 + t * 3;
            float s0 = sc_s[h];
            accV0 *= s0; accV1 *= s0; accV2 *= s0;
            #pragma unroll 4
            for (int j = 0; j < J; ++j) {
                float pj = logit_s[h * 17 + j];
                accV0 += pj * vpb[(size_t)j * VP3 + 0];
                accV1 += pj * vpb[(size_t)j * VP3 + 1];
                accV2 += pj * vpb[(size_t)j * VP3 + 2];
            }
        }
    }

    __syncthreads();
    if (t < H) l_s[t] = 1.0f / l_s[t];
    __syncthreads();

    float* F = feat + (size_t)bi * FEAT;
    if (t < HC) F[t] = accO * l_s[t >> 4];                       // o at [0,192)
    #pragma unroll
    for (int r = 0; r < 6; ++r) {                                 // opair at [576,2112)
        int flat = t + 256 * r;
        int h = flat >> 7, c = flat & 127;
        F[576 + h * CZ + c] = accP[r] * l_s[h];
    }
    if (t < H * PV) {                                             // op & onorm
        int h = t >> 3;
        float il = l_s[h];
        float o0 = accV0 * il - T[0], o1 = accV1 * il - T[1], o2 = accV2 * il - T[2];
        float n2 = 0.0f;
        #pragma unroll
        for (int x = 0; x < 3; ++x) {
            float rx = R[0 * 3 + x] * o0 + R[1 * 3 + x] * o1 + R[2 * 3 + x] * o2; // R^T
            F[HC + 96 * x + t] = rx;                              // op_x/y/z at [192,480)
            n2 += rx * rx;
        }
        F[480 + t] = fmaxf(sqrtf(n2), 1e-6f);                     // onorm at [480,576)
    }
}

// ---------------------------------------------------------------------------
// Kernel 3: out = feat @ Wout + bout, store f32 (reference output dtype).
// ---------------------------------------------------------------------------
__global__ __launch_bounds__(256) void k_out(
    const float* __restrict__ feat, const float* __restrict__ Wout, const float* __restrict__ bout,
    float* __restrict__ out)
{
    __shared__ float f_s[FEAT];
    const int t = threadIdx.x, bi = blockIdx.x;
    const float* frow = feat + (size_t)bi * FEAT;
    for (int q4 = t; q4 < FEAT / 4; q4 += 256) ((float4*)f_s)[q4] = ((const float4*)frow)[q4];
    __syncthreads();
    for (int col = t; col < CS; col += 256) {
        float acc = bout[col];
        #pragma unroll 4
        for (int k = 0; k < FEAT; ++k) acc += f_s[k] * Wout[(size_t)k * CS + col];
        out[(size_t)bi * CS + col] = acc;
    }
}

// ---------------------------------------------------------------------------
extern "C" void kernel_launch(void* const* d_in, const int* in_sizes, int n_in,
                              void* d_out, int out_size, void* d_ws, size_t ws_size,
                              hipStream_t stream)
{
    const float* s     = (const float*)d_in[0];
    const float* z     = (const float*)d_in[1];
    const float* rot   = (const float*)d_in[2];
    const float* trans = (const float*)d_in[3];
    const float* mask  = (const float*)d_in[4];
    const float* Wq    = (const float*)d_in[5];
    const float* bq    = (const float*)d_in[6];
    const float* Wkv   = (const float*)d_in[7];
    const float* bkv   = (const float*)d_in[8];
    const float* Wb    = (const float*)d_in[9];
    const float* bb    = (const float*)d_in[10];
    const float* Wqp   = (const float*)d_in[11];
    const float* bqp   = (const float*)d_in[12];
    const float* Wkvp  = (const float*)d_in[13];
    const float* bkvp  = (const float*)d_in[14];
    const float* gamma = (const float*)d_in[15];
    const float* Wout  = (const float*)d_in[16];
    const float* bout  = (const float*)d_in[17];

    // workspace layout (floats): total 3,342,336 (~13.4 MB)
    float* ws  = (float*)d_ws;
    float* qw  = ws;                 // 1024*192
    float* kw  = qw  + (size_t)B * N * HC;
    float* vw  = kw  + (size_t)B * N * HC;
    float* qpw = vw  + (size_t)B * N * HC;
    float* kpw = qpw + (size_t)B * N * QP3;
    float* vpw = kpw + (size_t)B * N * QP3;
    float* feat = vpw + (size_t)B * N * VP3;

    dim3 blk(256);
    hipLaunchKernelGGL(k_proj, dim3(B * N), blk, 0, stream,
                       s, rot, trans, Wq, bq, Wkv, bkv, Wqp, bqp, Wkvp, bkvp,
                       qw, kw, vw, qpw, kpw, vpw);
    hipLaunchKernelGGL(k_attn, dim3(B * N), blk, 0, stream,
                       z, rot, trans, mask, Wb, bb, gamma,
                       qw, kw, vw, qpw, kpw, vpw, feat);
    hipLaunchKernelGGL(k_out, dim3(B * N), blk, 0, stream,
                       feat, Wout, bout, (float*)d_out);
}

// Round 3
// 705.203 us; speedup vs baseline: 1.1534x; 1.1534x over previous
//
#include <hip/hip_runtime.h>
#include <hip/hip_bf16.h>

// Shapes (fixed for this problem)
constexpr int B = 2, N = 512, H = 12, C = 16, PQ = 4, PV = 8, CZ = 128, CS = 384;
constexpr int HC   = H * C;            // 192
constexpr int KVCOLS = 2 * HC;         // 384
constexpr int QPCOLS = 3 * PQ * H;     // 144
constexpr int KVPCOLS = 3 * (PQ + PV) * H; // 432
constexpr int QP3 = H * PQ * 3;        // 144 (layout [h][pq][x])
constexpr int VP3 = H * PV * 3;        // 288 (layout [h][pv][x])
constexpr int FEAT = (CZ + C + PV * 4) * H; // 2112
constexpr float QK_SCALE  = 0.14433756729740643f;  // (3*C)^-0.5
constexpr float INV_SQRT3 = 0.5773502691896258f;
constexpr float WC_IS3    = 0.13608276348795434f;  // sqrt(2/(9*PQ))*3^-0.5 = sqrt(1/54)

// ---------------------------------------------------------------------------
// Kernel 1: projections q,k,v (s@W) and rotated point projections qp,kp,vp
// One block per (b,i) row. 1024 blocks x 256 threads.
// ---------------------------------------------------------------------------
__global__ __launch_bounds__(256) void k_proj(
    const float* __restrict__ s, const float* __restrict__ rot, const float* __restrict__ trans,
    const float* __restrict__ Wq, const float* __restrict__ bq,
    const float* __restrict__ Wkv, const float* __restrict__ bkv,
    const float* __restrict__ Wqp, const float* __restrict__ bqp,
    const float* __restrict__ Wkvp, const float* __restrict__ bkvp,
    float* __restrict__ qw, float* __restrict__ kw, float* __restrict__ vw,
    float* __restrict__ qpw, float* __restrict__ kpw, float* __restrict__ vpw)
{
    __shared__ float s_s[CS];
    __shared__ float rawqp[QPCOLS];
    __shared__ float rawkvp[KVPCOLS];
    __shared__ float R[9], T[3];
    const int t = threadIdx.x;
    const int bi = blockIdx.x;

    const float* srow = s + (size_t)bi * CS;
    if (t < CS / 4) ((float4*)s_s)[t] = ((const float4*)srow)[t];
    if (t < 9) R[t] = rot[bi * 9 + t];
    if (t < 3) T[t] = trans[bi * 3 + t];
    __syncthreads();

    // q = s @ Wq + bq   (192 cols)
    if (t < HC) {
        float acc = bq[t];
        #pragma unroll 4
        for (int k = 0; k < CS; ++k) acc += s_s[k] * Wq[k * HC + t];
        qw[(size_t)bi * HC + t] = acc;
    }
    // kv = s @ Wkv + bkv (384 cols) -> split k / v per head
    for (int col = t; col < KVCOLS; col += 256) {
        float acc = bkv[col];
        #pragma unroll 4
        for (int k = 0; k < CS; ++k) acc += s_s[k] * Wkv[k * KVCOLS + col];
        int h = col >> 5, cc = col & 31;
        if (cc < C) kw[(size_t)bi * HC + h * C + cc] = acc;
        else        vw[(size_t)bi * HC + h * C + (cc - C)] = acc;
    }
    // qp raw (144 cols): chunk y is cols [y*48,(y+1)*48)
    if (t < QPCOLS) {
        float acc = bqp[t];
        #pragma unroll 4
        for (int k = 0; k < CS; ++k) acc += s_s[k] * Wqp[k * QPCOLS + t];
        rawqp[t] = acc;
    }
    // kvp raw (432 cols): chunk y is cols [y*144,(y+1)*144)
    for (int col = t; col < KVPCOLS; col += 256) {
        float acc = bkvp[col];
        #pragma unroll 4
        for (int k = 0; k < CS; ++k) acc += s_s[k] * Wkvp[k * KVPCOLS + col];
        rawkvp[col] = acc;
    }
    __syncthreads();

    // rotate qp: out[x] = T[x] + sum_y R[x][y]*raw[y*48+p], p = h*4+pq
    if (t < 48) {
        int p = t, h = p >> 2, pq = p & 3;
        float y0 = rawqp[0 * 48 + p], y1 = rawqp[1 * 48 + p], y2 = rawqp[2 * 48 + p];
        #pragma unroll
        for (int x = 0; x < 3; ++x) {
            float v = T[x] + R[x * 3 + 0] * y0 + R[x * 3 + 1] * y1 + R[x * 3 + 2] * y2;
            qpw[(size_t)bi * QP3 + h * 12 + pq * 3 + x] = v;
        }
    }
    // rotate kvp: p = h*12+pp; pp<4 -> kp else vp
    if (t < 144) {
        int p = t, h = p / 12, pp = p % 12;
        float y0 = rawkvp[0 * 144 + p], y1 = rawkvp[1 * 144 + p], y2 = rawkvp[2 * 144 + p];
        #pragma unroll
        for (int x = 0; x < 3; ++x) {
            float v = T[x] + R[x * 3 + 0] * y0 + R[x * 3 + 1] * y1 + R[x * 3 + 2] * y2;
            if (pp < PQ) kpw[(size_t)bi * QP3 + h * 12 + pp * 3 + x] = v;
            else         vpw[(size_t)bi * VP3 + h * 24 + (pp - PQ) * 3 + x] = v;
        }
    }
}

// ---------------------------------------------------------------------------
// Kernel 2: fused attention with online softmax — single pass over z.
// One block per (b,i). Chunks of J=16 keys.
// All LDS paddings are multiples of 4 floats so hot loops vectorize to b128.
// ---------------------------------------------------------------------------
constexpr int J = 16;
constexpr int ZP  = 136;   // z_s row stride (16B-aligned rows, 8-word skew)
constexpr int KP  = 196;   // k_s row stride
constexpr int KPP = 148;   // kp_s row stride
constexpr int LP  = 20;    // logit_s row stride

__global__ __launch_bounds__(256) void k_attn(
    const float* __restrict__ z, const float* __restrict__ rot, const float* __restrict__ trans,
    const float* __restrict__ seq_mask,
    const float* __restrict__ Wb, const float* __restrict__ bb, const float* __restrict__ gamma,
    const float* __restrict__ qw, const float* __restrict__ kw, const float* __restrict__ vw,
    const float* __restrict__ qpw, const float* __restrict__ kpw, const float* __restrict__ vpw,
    float* __restrict__ feat)
{
    __shared__ float z_s[J * ZP];
    __shared__ float k_s[J * KP];
    __shared__ float kp_s[J * KPP];
    __shared__ float logit_s[H * LP];
    __shared__ float q_s[HC], qp_s[QP3];
    __shared__ float Wbt_s[H * ZP];     // transposed: [h][c], c contiguous
    __shared__ float bb_s[H], pac_s[H], m_s[H], l_s[H], sc_s[H];
    __shared__ float R[9], T[3], mask_s[J];

    const int t = threadIdx.x;
    const int bi = blockIdx.x;
    const int b = bi >> 9;           // N = 512
    const int i = bi & (N - 1);

    if (t < HC)  q_s[t]  = qw[(size_t)bi * HC + t];
    if (t < QP3) qp_s[t] = qpw[(size_t)bi * QP3 + t];
    for (int idx = t; idx < CZ * H; idx += 256) {   // transpose Wb into [h][c]
        int c = idx & (CZ - 1), h = idx >> 7;
        Wbt_s[h * ZP + c] = Wb[c * H + h];
    }
    if (t < H) {
        bb_s[t] = bb[t];
        float g = gamma[t];
        float sp = fmaxf(g, 0.0f) + log1pf(expf(-fabsf(g)));   // stable softplus
        pac_s[t] = -0.5f * sp * WC_IS3;
        m_s[t] = -INFINITY;
        l_s[t] = 0.0f;
    }
    if (t < 9) R[t] = rot[bi * 9 + t];
    if (t < 3) T[t] = trans[bi * 3 + t];
    const float mask_i = seq_mask[bi];

    float accP[6] = {0, 0, 0, 0, 0, 0};   // opair: flat = t+256r -> h=flat>>7, c=flat&127
    float accO = 0.0f;                    // o: t<192 -> h=t>>4, c=t&15
    float accV0 = 0, accV1 = 0, accV2 = 0; // op: t<96 -> h=t>>3, p=t&7

    const float* zrow = z + ((size_t)b * N + i) * N * CZ;

    for (int j0 = 0; j0 < N; j0 += J) {
        __syncthreads();   // previous accumulate done reading LDS
        // ---- stage z, k, kp, mask (explicit float4 stores -> ds_write_b128) --
        for (int q4 = t; q4 < J * CZ / 4; q4 += 256) {
            int j = q4 >> 5, c4 = q4 & 31;
            float4 val = ((const float4*)(zrow + (size_t)(j0 + j) * CZ))[c4];
            *(float4*)&z_s[j * ZP + c4 * 4] = val;
        }
        for (int q4 = t; q4 < J * HC / 4; q4 += 256) {
            int j = q4 / 48, c4 = q4 % 48;
            float4 val = ((const float4*)(kw + (size_t)(b * N + j0 + j) * HC))[c4];
            *(float4*)&k_s[j * KP + c4 * 4] = val;
        }
        for (int q4 = t; q4 < J * QP3 / 4; q4 += 256) {
            int j = q4 / 36, c4 = q4 % 36;
            float4 val = ((const float4*)(kpw + (size_t)(b * N + j0 + j) * QP3))[c4];
            *(float4*)&kp_s[j * KPP + c4 * 4] = val;
        }
        if (t < J) mask_s[t] = seq_mask[b * N + j0 + t];
        __syncthreads();

        // ---- logits: 192 threads, (h = t>>4, j = t&15) ----
        if (t < H * J) {
            int j = t & (J - 1), h = t >> 4;
            const float* zr = &z_s[j * ZP];
            const float* wr = &Wbt_s[h * ZP];
            float bp = bb_s[h];
            #pragma unroll 8
            for (int c = 0; c < CZ; ++c) bp += zr[c] * wr[c];
            float qk = 0.0f;
            #pragma unroll
            for (int c = 0; c < C; ++c) qk += q_s[h * C + c] * k_s[j * KP + h * C + c];
            float d2 = 0.0f;
            #pragma unroll
            for (int e = 0; e < 12; ++e) {
                float d = qp_s[h * 12 + e] - kp_s[j * KPP + h * 12 + e];
                d2 += d * d;
            }
            logit_s[h * LP + j] = QK_SCALE * qk + INV_SQRT3 * bp + pac_s[h] * d2
                                + 100000.0f * (mask_i * mask_s[j] - 1.0f);
        }
        __syncthreads();
        // ---- chunk max + rescale factor (12 threads) ----
        if (t < H) {
            float cm = -INFINITY;
            for (int j = 0; j < J; ++j) cm = fmaxf(cm, logit_s[t * LP + j]);
            float mnew = fmaxf(m_s[t], cm);
            sc_s[t] = expf(m_s[t] - mnew);   // exp(-inf)=0 on first chunk
            m_s[t] = mnew;
        }
        __syncthreads();
        // ---- exp in parallel (192 threads) ----
        if (t < H * J) {
            int j = t & (J - 1), h = t >> 4;
            logit_s[h * LP + j] = expf(logit_s[h * LP + j] - m_s[h]);
        }
        __syncthreads();
        if (t < H) {
            float ssum = 0.0f;
            for (int j = 0; j < J; ++j) ssum += logit_s[t * LP + j];
            l_s[t] = l_s[t] * sc_s[t] + ssum;
        }
        __syncthreads();

        // ---- accumulate ----
        #pragma unroll
        for (int r = 0; r < 6; ++r) {        // opair
            int flat = t + 256 * r;
            int h = flat >> 7, c = flat & 127;
            float a = accP[r] * sc_s[h];
            #pragma unroll
            for (int jq = 0; jq < 4; ++jq) {
                float4 p4 = *(const float4*)&logit_s[h * LP + jq * 4];
                a += p4.x * z_s[(jq * 4 + 0) * ZP + c];
                a += p4.y * z_s[(jq * 4 + 1) * ZP + c];
                a += p4.z * z_s[(jq * 4 + 2) * ZP + c];
                a += p4.w * z_s[(jq * 4 + 3) * ZP + c];
            }
            accP[r] = a;
        }
        if (t < HC) {                        // o (v from global, L2-resident)
            int h = t >> 4;
            const float* vb = vw + (size_t)(b * N + j0) * HC + t;
            float a = accO * sc_s[h];
            #pragma unroll
            for (int jq = 0; jq < 4; ++jq) {
                float4 p4 = *(const float4*)&logit_s[h * LP + jq * 4];
                a += p4.x * vb[(size_t)(jq * 4 + 0) * HC];
                a += p4.y * vb[(size_t)(jq * 4 + 1) * HC];
                a += p4.z * vb[(size_t)(jq * 4 + 2) * HC];
                a += p4.w * vb[(size_t)(jq * 4 + 3) * HC];
            }
            accO = a;
        }
        if (t < H * PV) {                    // op (vp from global, L2-resident)
            int h = t >> 3;
            const float* vpb = vpw + (size_t)(b * N + j0) * VP3 + t * 3;
            float s0 = sc_s[h];
            accV0 *= s0; accV1 *= s0; accV2 *= s0;
            #pragma unroll 4
            for (int j = 0; j < J; ++j) {
                float pj = logit_s[h * LP + j];
                accV0 += pj * vpb[(size_t)j * VP3 + 0];
                accV1 += pj * vpb[(size_t)j * VP3 + 1];
                accV2 += pj * vpb[(size_t)j * VP3 + 2];
            }
        }
    }

    __syncthreads();
    if (t < H) l_s[t] = 1.0f / l_s[t];
    __syncthreads();

    float* F = feat + (size_t)bi * FEAT;
    if (t < HC) F[t] = accO * l_s[t >> 4];                       // o at [0,192)
    #pragma unroll
    for (int r = 0; r < 6; ++r) {                                 // opair at [576,2112)
        int flat = t + 256 * r;
        int h = flat >> 7, c = flat & 127;
        F[576 + h * CZ + c] = accP[r] * l_s[h];
    }
    if (t < H * PV) {                                             // op & onorm
        int h = t >> 3;
        float il = l_s[h];
        float o0 = accV0 * il - T[0], o1 = accV1 * il - T[1], o2 = accV2 * il - T[2];
        float n2 = 0.0f;
        #pragma unroll
        for (int x = 0; x < 3; ++x) {
            float rx = R[0 * 3 + x] * o0 + R[1 * 3 + x] * o1 + R[2 * 3 + x] * o2; // R^T
            F[HC + 96 * x + t] = rx;                              // op_x/y/z at [192,480)
            n2 += rx * rx;
        }
        F[480 + t] = fmaxf(sqrtf(n2), 1e-6f);                     // onorm at [480,576)
    }
}

// ---------------------------------------------------------------------------
// Kernel 3: tiled f32 GEMM  out[1024,384] = feat[1024,2112] @ Wout + bout.
// BM=32, BN=64, Kc=96. Grid 32x6=192 blocks, 256 threads.
// Thread: 2 rows x 4 cols (float4), 6 b128 LDS reads per 32 FMA.
// ---------------------------------------------------------------------------
constexpr int BM = 32, BN = 64, KC = 96;
constexpr int FP = 100;   // f_s row stride (pad, 16B-aligned rows)

__global__ __launch_bounds__(256) void k_out(
    const float* __restrict__ feat, const float* __restrict__ Wout, const float* __restrict__ bout,
    float* __restrict__ out)
{
    __shared__ float f_s[BM * FP];       // 12.8 KB
    __shared__ float w_s[KC * BN];       // 24.6 KB
    const int t = threadIdx.x;
    const int bm = (blockIdx.x / 6) * BM;
    const int bn = (blockIdx.x % 6) * BN;

    const int cg = t & 15;               // 16 col groups * 4 = 64 cols
    const int rp = t >> 4;               // rows rp and rp+16
    const int r0 = rp, r1 = rp + 16;

    float4 acc0 = {0, 0, 0, 0}, acc1 = {0, 0, 0, 0};

    for (int k0 = 0; k0 < FEAT; k0 += KC) {
        __syncthreads();
        // stage feat tile 32 x 96 (768 float4)
        for (int idx = t; idx < BM * KC / 4; idx += 256) {
            int row = idx / (KC / 4), c4 = idx % (KC / 4);
            *(float4*)&f_s[row * FP + c4 * 4] =
                *(const float4*)&feat[(size_t)(bm + row) * FEAT + k0 + c4 * 4];
        }
        // stage Wout tile 96 x 64 (1536 float4)
        for (int idx = t; idx < KC * BN / 4; idx += 256) {
            int row = idx >> 4, c4 = idx & 15;
            *(float4*)&w_s[row * BN + c4 * 4] =
                *(const float4*)&Wout[(size_t)(k0 + row) * CS + bn + c4 * 4];
        }
        __syncthreads();

        #pragma unroll 4
        for (int kq = 0; kq < KC / 4; ++kq) {
            float4 fa = *(const float4*)&f_s[r0 * FP + kq * 4];
            float4 fb = *(const float4*)&f_s[r1 * FP + kq * 4];
            const float fav[4] = {fa.x, fa.y, fa.z, fa.w};
            const float fbv[4] = {fb.x, fb.y, fb.z, fb.w};
            #pragma unroll
            for (int e = 0; e < 4; ++e) {
                float4 w4 = *(const float4*)&w_s[(kq * 4 + e) * BN + cg * 4];
                acc0.x += fav[e] * w4.x; acc0.y += fav[e] * w4.y;
                acc0.z += fav[e] * w4.z; acc0.w += fav[e] * w4.w;
                acc1.x += fbv[e] * w4.x; acc1.y += fbv[e] * w4.y;
                acc1.z += fbv[e] * w4.z; acc1.w += fbv[e] * w4.w;
            }
        }
    }

    float4 bo = *(const float4*)&bout[bn + cg * 4];
    acc0.x += bo.x; acc0.y += bo.y; acc0.z += bo.z; acc0.w += bo.w;
    acc1.x += bo.x; acc1.y += bo.y; acc1.z += bo.z; acc1.w += bo.w;
    *(float4*)&out[(size_t)(bm + r0) * CS + bn + cg * 4] = acc0;
    *(float4*)&out[(size_t)(bm + r1) * CS + bn + cg * 4] = acc1;
}

// ---------------------------------------------------------------------------
extern "C" void kernel_launch(void* const* d_in, const int* in_sizes, int n_in,
                              void* d_out, int out_size, void* d_ws, size_t ws_size,
                              hipStream_t stream)
{
    const float* s     = (const float*)d_in[0];
    const float* z     = (const float*)d_in[1];
    const float* rot   = (const float*)d_in[2];
    const float* trans = (const float*)d_in[3];
    const float* mask  = (const float*)d_in[4];
    const float* Wq    = (const float*)d_in[5];
    const float* bq    = (const float*)d_in[6];
    const float* Wkv   = (const float*)d_in[7];
    const float* bkv   = (const float*)d_in[8];
    const float* Wb    = (const float*)d_in[9];
    const float* bb    = (const float*)d_in[10];
    const float* Wqp   = (const float*)d_in[11];
    const float* bqp   = (const float*)d_in[12];
    const float* Wkvp  = (const float*)d_in[13];
    const float* bkvp  = (const float*)d_in[14];
    const float* gamma = (const float*)d_in[15];
    const float* Wout  = (const float*)d_in[16];
    const float* bout  = (const float*)d_in[17];

    // workspace layout (floats): total 3,342,336 (~13.4 MB)
    float* ws  = (float*)d_ws;
    float* qw  = ws;                 // 1024*192
    float* kw  = qw  + (size_t)B * N * HC;
    float* vw  = kw  + (size_t)B * N * HC;
    float* qpw = vw  + (size_t)B * N * HC;
    float* kpw = qpw + (size_t)B * N * QP3;
    float* vpw = kpw + (size_t)B * N * QP3;
    float* feat = vpw + (size_t)B * N * VP3;

    dim3 blk(256);
    hipLaunchKernelGGL(k_proj, dim3(B * N), blk, 0, stream,
                       s, rot, trans, Wq, bq, Wkv, bkv, Wqp, bqp, Wkvp, bkvp,
                       qw, kw, vw, qpw, kpw, vpw);
    hipLaunchKernelGGL(k_attn, dim3(B * N), blk, 0, stream,
                       z, rot, trans, mask, Wb, bb, gamma,
                       qw, kw, vw, qpw, kpw, vpw, feat);
    hipLaunchKernelGGL(k_out, dim3(192), blk, 0, stream,
                       feat, Wout, bout, (float*)d_out);
}

// Round 4
// 610.876 us; speedup vs baseline: 1.3315x; 1.1544x over previous
//
#include <hip/hip_runtime.h>
#include <hip/hip_bf16.h>

// Shapes (fixed for this problem)
constexpr int B = 2, N = 512, H = 12, C = 16, PQ = 4, PV = 8, CZ = 128, CS = 384;
constexpr int HC   = H * C;            // 192
constexpr int KVCOLS = 2 * HC;         // 384
constexpr int QPCOLS = 3 * PQ * H;     // 144
constexpr int KVPCOLS = 3 * (PQ + PV) * H; // 432
constexpr int QP3 = H * PQ * 3;        // 144 (layout [h][pq][x])
constexpr int VP3 = H * PV * 3;        // 288 (layout [h][pv][x])
constexpr int KPX = 160;               // kp augmented row: 144 kp + 12 kpsq + 4 zero
constexpr int FEAT = (CZ + C + PV * 4) * H; // 2112
constexpr float QK_SCALE  = 0.14433756729740643f;  // (3*C)^-0.5
constexpr float INV_SQRT3 = 0.5773502691896258f;
constexpr float WC_IS3    = 0.13608276348795434f;  // sqrt(2/(9*PQ))*3^-0.5

using f32x4 = __attribute__((ext_vector_type(4))) float;
using s16x8 = __attribute__((ext_vector_type(8))) short;
using s16x4 = __attribute__((ext_vector_type(4))) short;

__device__ __forceinline__ short f2b(float f) {
    union { __hip_bfloat16 b; short s; } u;
    u.b = __float2bfloat16(f);
    return u.s;
}

// ---------------------------------------------------------------------------
// Kernel 1: projections q,k,v and rotated point projections qp,kp(+sq),vp
// ---------------------------------------------------------------------------
__global__ __launch_bounds__(256) void k_proj(
    const float* __restrict__ s, const float* __restrict__ rot, const float* __restrict__ trans,
    const float* __restrict__ Wq, const float* __restrict__ bq,
    const float* __restrict__ Wkv, const float* __restrict__ bkv,
    const float* __restrict__ Wqp, const float* __restrict__ bqp,
    const float* __restrict__ Wkvp, const float* __restrict__ bkvp,
    float* __restrict__ qw, float* __restrict__ kw, float* __restrict__ vw,
    float* __restrict__ qpw, float* __restrict__ kpx, float* __restrict__ vpw)
{
    __shared__ float s_s[CS];
    __shared__ float rawqp[QPCOLS];
    __shared__ float rawkvp[KVPCOLS];
    __shared__ float sq_s[48];
    __shared__ float R[9], T[3];
    const int t = threadIdx.x;
    const int bi = blockIdx.x;

    const float* srow = s + (size_t)bi * CS;
    if (t < CS / 4) ((float4*)s_s)[t] = ((const float4*)srow)[t];
    if (t < 9) R[t] = rot[bi * 9 + t];
    if (t < 3) T[t] = trans[bi * 3 + t];
    __syncthreads();

    if (t < HC) {
        float acc = bq[t];
        #pragma unroll 4
        for (int k = 0; k < CS; ++k) acc += s_s[k] * Wq[k * HC + t];
        qw[(size_t)bi * HC + t] = acc;
    }
    for (int col = t; col < KVCOLS; col += 256) {
        float acc = bkv[col];
        #pragma unroll 4
        for (int k = 0; k < CS; ++k) acc += s_s[k] * Wkv[k * KVCOLS + col];
        int h = col >> 5, cc = col & 31;
        if (cc < C) kw[(size_t)bi * HC + h * C + cc] = acc;
        else        vw[(size_t)bi * HC + h * C + (cc - C)] = acc;
    }
    if (t < QPCOLS) {
        float acc = bqp[t];
        #pragma unroll 4
        for (int k = 0; k < CS; ++k) acc += s_s[k] * Wqp[k * QPCOLS + t];
        rawqp[t] = acc;
    }
    for (int col = t; col < KVPCOLS; col += 256) {
        float acc = bkvp[col];
        #pragma unroll 4
        for (int k = 0; k < CS; ++k) acc += s_s[k] * Wkvp[k * KVPCOLS + col];
        rawkvp[col] = acc;
    }
    __syncthreads();

    if (t < 48) {
        int p = t, h = p >> 2, pq = p & 3;
        float y0 = rawqp[0 * 48 + p], y1 = rawqp[1 * 48 + p], y2 = rawqp[2 * 48 + p];
        #pragma unroll
        for (int x = 0; x < 3; ++x) {
            float v = T[x] + R[x * 3 + 0] * y0 + R[x * 3 + 1] * y1 + R[x * 3 + 2] * y2;
            qpw[(size_t)bi * QP3 + h * 12 + pq * 3 + x] = v;
        }
    }
    if (t < 144) {
        int p = t, h = p / 12, pp = p % 12;
        float y0 = rawkvp[0 * 144 + p], y1 = rawkvp[1 * 144 + p], y2 = rawkvp[2 * 144 + p];
        float vals[3]; float ss = 0.0f;
        #pragma unroll
        for (int x = 0; x < 3; ++x) {
            float v = T[x] + R[x * 3 + 0] * y0 + R[x * 3 + 1] * y1 + R[x * 3 + 2] * y2;
            vals[x] = v; ss += v * v;
        }
        if (pp < PQ) {
            #pragma unroll
            for (int x = 0; x < 3; ++x) kpx[(size_t)bi * KPX + h * 12 + pp * 3 + x] = vals[x];
            sq_s[h * 4 + pp] = ss;
        } else {
            #pragma unroll
            for (int x = 0; x < 3; ++x) vpw[(size_t)bi * VP3 + h * 24 + (pp - PQ) * 3 + x] = vals[x];
        }
    }
    __syncthreads();
    if (t < 12) kpx[(size_t)bi * KPX + 144 + t] =
        sq_s[t * 4] + sq_s[t * 4 + 1] + sq_s[t * 4 + 2] + sq_s[t * 4 + 3];
    if (t >= 12 && t < 16) kpx[(size_t)bi * KPX + 144 + t] = 0.0f;
}

// ---------------------------------------------------------------------------
// Kernel 2: fused attention. One block per (b,i); 4 waves, wave w owns
// j in [w*128, w*128+128), 8 chunks of 16. No barriers in the main loop.
// Logits: 15 chained mfma_f32_16x16x32_bf16 (bpair + qk-blockdiag + pa).
// opair: mfma_f32_16x16x16bf16_1k with P already in A-fragment layout.
// ---------------------------------------------------------------------------
__global__ __launch_bounds__(256) void k_attn(
    const float* __restrict__ z, const float* __restrict__ rot, const float* __restrict__ trans,
    const float* __restrict__ seq_mask,
    const float* __restrict__ Wb, const float* __restrict__ bb, const float* __restrict__ gamma,
    const float* __restrict__ qw, const float* __restrict__ kw, const float* __restrict__ vw,
    const float* __restrict__ qpw, const float* __restrict__ kpx, const float* __restrict__ vpw,
    float* __restrict__ feat)
{
    __shared__ float P_s[4][12][16];
    __shared__ float sc_s[4][16];
    __shared__ float ml_s[4][16];
    __shared__ float ll_s[4][16];
    __shared__ float opm_s[4][1536];
    __shared__ float om_s[4][192];
    __shared__ float vpm_s[4][96][3];
    __shared__ float Linv_s[12];
    __shared__ float M_s[12];
    __shared__ float R_s[9], T_s[3];

    const int t = threadIdx.x;
    const int w  = t >> 6;
    const int l  = t & 63;
    const int lg = l >> 4;        // lane group 0..3
    const int m15 = l & 15;       // MFMA row/col-within-16 index
    const int bi = blockIdx.x;
    const int b  = bi >> 9;       // N = 512
    const int i  = bi & (N - 1);

    if (t < 9) R_s[t] = rot[bi * 9 + t];
    if (t < 3) T_s[t] = trans[bi * 3 + t];

    const bool hv = (m15 < 12);
    const int hcl = hv ? m15 : 0;                 // clamped h for safe loads
    float g0 = gamma[hcl];
    float sp = fmaxf(g0, 0.0f) + log1pf(expf(-fabsf(g0)));
    float pac = hv ? (-0.5f * sp * WC_IS3) : 0.0f;
    float qpsq = 0.0f;
    #pragma unroll
    for (int e = 0; e < 12; ++e) {
        float qv = qpw[(size_t)bi * QP3 + hcl * 12 + e];
        qpsq += qv * qv;
    }
    const float constH = hv ? (INV_SQRT3 * bb[hcl] + pac * qpsq) : 0.0f;
    const float mask_i = seq_mask[bi];

    // ---- B-fragments (register-resident, per-lane) ----
    s16x8 WbB[4], QB[6], PAB[5];
    #pragma unroll
    for (int kk = 0; kk < 4; ++kk) {
        s16x8 f;
        #pragma unroll
        for (int e = 0; e < 8; ++e) {
            int c = kk * 32 + lg * 8 + e;
            float v = Wb[c * 12 + hcl];
            f[e] = f2b(hv ? INV_SQRT3 * v : 0.0f);
        }
        WbB[kk] = f;
    }
    #pragma unroll
    for (int kk = 0; kk < 6; ++kk) {
        s16x8 f;
        #pragma unroll
        for (int e = 0; e < 8; ++e) {
            int c = kk * 32 + lg * 8 + e;
            float v = qw[(size_t)bi * HC + c];
            f[e] = f2b((hv && (c >> 4) == m15) ? QK_SCALE * v : 0.0f);
        }
        QB[kk] = f;
    }
    #pragma unroll
    for (int kk = 0; kk < 5; ++kk) {
        s16x8 f;
        #pragma unroll
        for (int e = 0; e < 8; ++e) {
            int kg = kk * 32 + lg * 8 + e;
            float v = 0.0f;
            if (hv && kg < 144) {
                int hp = kg / 12, ep = kg - hp * 12;
                float qv = qpw[(size_t)bi * QP3 + hcl * 12 + ep];
                v = (hp == m15) ? (-2.0f * pac * qv) : 0.0f;
            } else if (hv && kg < 156) {
                v = ((kg - 144) == m15) ? pac : 0.0f;
            }
            f[e] = f2b(v);
        }
        PAB[kk] = f;
    }

    float m_run = -INFINITY, l_run = 0.0f;
    f32x4 opacc[8];
    #pragma unroll
    for (int ct = 0; ct < 8; ++ct) opacc[ct] = (f32x4){0.0f, 0.0f, 0.0f, 0.0f};
    float oacc[3] = {0.0f, 0.0f, 0.0f};
    float vpacc[2][3] = {{0,0,0},{0,0,0}};

    const size_t zbase = ((size_t)b * N + i) * (size_t)(N * CZ);
    const int jw = w * 128;

    for (int jc = 0; jc < 8; ++jc) {
        const int j0 = jw + jc * 16;
        // ---- A-fragment loads (global -> reg, f32 -> bf16) ----
        const float* zA = z   + zbase + (size_t)(j0 + m15) * CZ  + lg * 8;
        const float* kA = kw  + (size_t)(b * N + j0 + m15) * HC  + lg * 8;
        const float* pA = kpx + (size_t)(b * N + j0 + m15) * KPX + lg * 8;
        s16x8 zf[4], kf[6], pf[5];
        #pragma unroll
        for (int kk = 0; kk < 4; ++kk) {
            float4 u0 = *(const float4*)(zA + kk * 32);
            float4 u1 = *(const float4*)(zA + kk * 32 + 4);
            s16x8 f;
            f[0]=f2b(u0.x); f[1]=f2b(u0.y); f[2]=f2b(u0.z); f[3]=f2b(u0.w);
            f[4]=f2b(u1.x); f[5]=f2b(u1.y); f[6]=f2b(u1.z); f[7]=f2b(u1.w);
            zf[kk] = f;
        }
        #pragma unroll
        for (int kk = 0; kk < 6; ++kk) {
            float4 u0 = *(const float4*)(kA + kk * 32);
            float4 u1 = *(const float4*)(kA + kk * 32 + 4);
            s16x8 f;
            f[0]=f2b(u0.x); f[1]=f2b(u0.y); f[2]=f2b(u0.z); f[3]=f2b(u0.w);
            f[4]=f2b(u1.x); f[5]=f2b(u1.y); f[6]=f2b(u1.z); f[7]=f2b(u1.w);
            kf[kk] = f;
        }
        #pragma unroll
        for (int kk = 0; kk < 5; ++kk) {
            float4 u0 = *(const float4*)(pA + kk * 32);
            float4 u1 = *(const float4*)(pA + kk * 32 + 4);
            s16x8 f;
            f[0]=f2b(u0.x); f[1]=f2b(u0.y); f[2]=f2b(u0.z); f[3]=f2b(u0.w);
            f[4]=f2b(u1.x); f[5]=f2b(u1.y); f[6]=f2b(u1.z); f[7]=f2b(u1.w);
            pf[kk] = f;
        }
        // ---- chained logit MFMAs: D[j][h] ----
        f32x4 acc = (f32x4){0.0f, 0.0f, 0.0f, 0.0f};
        #pragma unroll
        for (int kk = 0; kk < 4; ++kk)
            acc = __builtin_amdgcn_mfma_f32_16x16x32_bf16(zf[kk], WbB[kk], acc, 0, 0, 0);
        #pragma unroll
        for (int kk = 0; kk < 6; ++kk)
            acc = __builtin_amdgcn_mfma_f32_16x16x32_bf16(kf[kk], QB[kk], acc, 0, 0, 0);
        #pragma unroll
        for (int kk = 0; kk < 5; ++kk)
            acc = __builtin_amdgcn_mfma_f32_16x16x32_bf16(pf[kk], PAB[kk], acc, 0, 0, 0);

        // ---- logits + online softmax (lane: h = m15, rows j = j0+lg*4+r) ----
        float lo[4]; float cm = -INFINITY;
        #pragma unroll
        for (int r = 0; r < 4; ++r) {
            int j = j0 + lg * 4 + r;
            float mb = 100000.0f * (mask_i * seq_mask[b * N + j] - 1.0f);
            lo[r] = acc[r] + constH + mb;
            cm = fmaxf(cm, lo[r]);
        }
        cm = fmaxf(cm, __shfl_xor(cm, 16, 64));
        cm = fmaxf(cm, __shfl_xor(cm, 32, 64));
        float mnew = fmaxf(m_run, cm);
        float sc = __expf(m_run - mnew);
        m_run = mnew;
        float p[4]; float ps = 0.0f;
        #pragma unroll
        for (int r = 0; r < 4; ++r) { p[r] = __expf(lo[r] - mnew); ps += p[r]; }
        ps += __shfl_xor(ps, 16, 64);
        ps += __shfl_xor(ps, 32, 64);
        l_run = l_run * sc + ps;

        if (lg == 0) sc_s[w][m15] = sc;
        if (hv) {
            #pragma unroll
            for (int r = 0; r < 4; ++r) P_s[w][m15][lg * 4 + r] = p[r];
        }

        // ---- opair: D[h][c], A = P (already in-layout), B = z col-slices ----
        s16x4 pfrag;
        #pragma unroll
        for (int r = 0; r < 4; ++r) pfrag[r] = hv ? f2b(p[r]) : (short)0;
        float s4[4];
        #pragma unroll
        for (int r = 0; r < 4; ++r) s4[r] = sc_s[w][lg * 4 + r];
        const float* zB = z + zbase + (size_t)(j0 + lg * 4) * CZ + m15;
        #pragma unroll
        for (int ct = 0; ct < 8; ++ct) {
            s16x4 bfr;
            #pragma unroll
            for (int e = 0; e < 4; ++e) bfr[e] = f2b(zB[(size_t)e * CZ + ct * 16]);
            f32x4 oa = opacc[ct];
            #pragma unroll
            for (int r = 0; r < 4; ++r) oa[r] *= s4[r];
            opacc[ct] = __builtin_amdgcn_mfma_f32_16x16x16bf16_1k(pfrag, bfr, oa, 0, 0, 0);
        }

        // ---- o: VALU from P_s + v (L2) ----
        #pragma unroll
        for (int rr = 0; rr < 3; ++rr) {
            int oi = l + 64 * rr; int oh = oi >> 4, oc = oi & 15;
            float so = sc_s[w][oh];
            const float* vb = vw + (size_t)(b * N + j0) * HC + oh * 16 + oc;
            const float* Pr = &P_s[w][oh][0];
            float a = oacc[rr] * so;
            #pragma unroll
            for (int j = 0; j < 16; ++j) a += Pr[j] * vb[(size_t)j * HC];
            oacc[rr] = a;
        }
        // ---- op: VALU from P_s + vp (L2) ----
        #pragma unroll
        for (int rr = 0; rr < 2; ++rr) {
            int oi = l + 64 * rr;
            if (oi < 96) {
                int oh = oi >> 3;
                float so = sc_s[w][oh];
                const float* vpb = vpw + (size_t)(b * N + j0) * VP3 + oi * 3;
                const float* Pr = &P_s[w][oh][0];
                float a0 = vpacc[rr][0] * so, a1 = vpacc[rr][1] * so, a2 = vpacc[rr][2] * so;
                #pragma unroll
                for (int j = 0; j < 16; ++j) {
                    float pj = Pr[j];
                    const float* vv = vpb + (size_t)j * VP3;
                    a0 += pj * vv[0]; a1 += pj * vv[1]; a2 += pj * vv[2];
                }
                vpacc[rr][0] = a0; vpacc[rr][1] = a1; vpacc[rr][2] = a2;
            }
        }
    }

    // ---- merge the 4 waves ----
    if (lg == 0) { ml_s[w][m15] = m_run; ll_s[w][m15] = l_run; }
    __syncthreads();
    if (t < 12) {
        float M = ml_s[0][t];
        M = fmaxf(M, ml_s[1][t]); M = fmaxf(M, ml_s[2][t]); M = fmaxf(M, ml_s[3][t]);
        float Lt = 0.0f;
        #pragma unroll
        for (int ww = 0; ww < 4; ++ww) Lt += ll_s[ww][t] * __expf(ml_s[ww][t] - M);
        M_s[t] = M;
        Linv_s[t] = 1.0f / Lt;
    }
    __syncthreads();
    {
        float s4[4];
        #pragma unroll
        for (int r = 0; r < 4; ++r) {
            int hr = lg * 4 + r;
            s4[r] = (hr < 12) ? __expf(ml_s[w][hr] - M_s[hr]) : 0.0f;
        }
        #pragma unroll
        for (int ct = 0; ct < 8; ++ct) {
            #pragma unroll
            for (int r = 0; r < 4; ++r) {
                int hr = lg * 4 + r;
                if (hr < 12) opm_s[w][hr * 128 + ct * 16 + m15] = opacc[ct][r] * s4[r];
            }
        }
        #pragma unroll
        for (int rr = 0; rr < 3; ++rr) {
            int oi = l + 64 * rr; int oh = oi >> 4;
            om_s[w][oi] = oacc[rr] * __expf(ml_s[w][oh] - M_s[oh]);
        }
        #pragma unroll
        for (int rr = 0; rr < 2; ++rr) {
            int oi = l + 64 * rr;
            if (oi < 96) {
                int oh = oi >> 3;
                float sw = __expf(ml_s[w][oh] - M_s[oh]);
                vpm_s[w][oi][0] = vpacc[rr][0] * sw;
                vpm_s[w][oi][1] = vpacc[rr][1] * sw;
                vpm_s[w][oi][2] = vpacc[rr][2] * sw;
            }
        }
    }
    __syncthreads();

    float* F = feat + (size_t)bi * FEAT;
    if (t < HC) F[t] = (om_s[0][t] + om_s[1][t] + om_s[2][t] + om_s[3][t]) * Linv_s[t >> 4];
    #pragma unroll
    for (int r = 0; r < 6; ++r) {
        int v = t + 256 * r; int hh = v >> 7;
        F[576 + v] = (opm_s[0][v] + opm_s[1][v] + opm_s[2][v] + opm_s[3][v]) * Linv_s[hh];
    }
    if (t < 96) {
        int hh = t >> 3; float il = Linv_s[hh];
        float o0 = (vpm_s[0][t][0] + vpm_s[1][t][0] + vpm_s[2][t][0] + vpm_s[3][t][0]) * il - T_s[0];
        float o1 = (vpm_s[0][t][1] + vpm_s[1][t][1] + vpm_s[2][t][1] + vpm_s[3][t][1]) * il - T_s[1];
        float o2 = (vpm_s[0][t][2] + vpm_s[1][t][2] + vpm_s[2][t][2] + vpm_s[3][t][2]) * il - T_s[2];
        float n2 = 0.0f;
        #pragma unroll
        for (int x = 0; x < 3; ++x) {
            float rx = R_s[0 * 3 + x] * o0 + R_s[1 * 3 + x] * o1 + R_s[2 * 3 + x] * o2; // R^T
            F[HC + 96 * x + t] = rx;
            n2 += rx * rx;
        }
        F[480 + t] = fmaxf(sqrtf(n2), 1e-6f);
    }
}

// ---------------------------------------------------------------------------
// Kernel 3: tiled f32 GEMM  out[1024,384] = feat[1024,2112] @ Wout + bout.
// ---------------------------------------------------------------------------
constexpr int BM = 32, BN = 64, KC = 96;
constexpr int FP = 100;

__global__ __launch_bounds__(256) void k_out(
    const float* __restrict__ feat, const float* __restrict__ Wout, const float* __restrict__ bout,
    float* __restrict__ out)
{
    __shared__ float f_s[BM * FP];
    __shared__ float w_s[KC * BN];
    const int t = threadIdx.x;
    const int bm = (blockIdx.x / 6) * BM;
    const int bn = (blockIdx.x % 6) * BN;

    const int cg = t & 15;
    const int rp = t >> 4;
    const int r0 = rp, r1 = rp + 16;

    float4 acc0 = {0, 0, 0, 0}, acc1 = {0, 0, 0, 0};

    for (int k0 = 0; k0 < FEAT; k0 += KC) {
        __syncthreads();
        for (int idx = t; idx < BM * KC / 4; idx += 256) {
            int row = idx / (KC / 4), c4 = idx % (KC / 4);
            *(float4*)&f_s[row * FP + c4 * 4] =
                *(const float4*)&feat[(size_t)(bm + row) * FEAT + k0 + c4 * 4];
        }
        for (int idx = t; idx < KC * BN / 4; idx += 256) {
            int row = idx >> 4, c4 = idx & 15;
            *(float4*)&w_s[row * BN + c4 * 4] =
                *(const float4*)&Wout[(size_t)(k0 + row) * CS + bn + c4 * 4];
        }
        __syncthreads();

        #pragma unroll 4
        for (int kq = 0; kq < KC / 4; ++kq) {
            float4 fa = *(const float4*)&f_s[r0 * FP + kq * 4];
            float4 fb = *(const float4*)&f_s[r1 * FP + kq * 4];
            const float fav[4] = {fa.x, fa.y, fa.z, fa.w};
            const float fbv[4] = {fb.x, fb.y, fb.z, fb.w};
            #pragma unroll
            for (int e = 0; e < 4; ++e) {
                float4 w4 = *(const float4*)&w_s[(kq * 4 + e) * BN + cg * 4];
                acc0.x += fav[e] * w4.x; acc0.y += fav[e] * w4.y;
                acc0.z += fav[e] * w4.z; acc0.w += fav[e] * w4.w;
                acc1.x += fbv[e] * w4.x; acc1.y += fbv[e] * w4.y;
                acc1.z += fbv[e] * w4.z; acc1.w += fbv[e] * w4.w;
            }
        }
    }

    float4 bo = *(const float4*)&bout[bn + cg * 4];
    acc0.x += bo.x; acc0.y += bo.y; acc0.z += bo.z; acc0.w += bo.w;
    acc1.x += bo.x; acc1.y += bo.y; acc1.z += bo.z; acc1.w += bo.w;
    *(float4*)&out[(size_t)(bm + r0) * CS + bn + cg * 4] = acc0;
    *(float4*)&out[(size_t)(bm + r1) * CS + bn + cg * 4] = acc1;
}

// ---------------------------------------------------------------------------
extern "C" void kernel_launch(void* const* d_in, const int* in_sizes, int n_in,
                              void* d_out, int out_size, void* d_ws, size_t ws_size,
                              hipStream_t stream)
{
    const float* s     = (const float*)d_in[0];
    const float* z     = (const float*)d_in[1];
    const float* rot   = (const float*)d_in[2];
    const float* trans = (const float*)d_in[3];
    const float* mask  = (const float*)d_in[4];
    const float* Wq    = (const float*)d_in[5];
    const float* bq    = (const float*)d_in[6];
    const float* Wkv   = (const float*)d_in[7];
    const float* bkv   = (const float*)d_in[8];
    const float* Wb    = (const float*)d_in[9];
    const float* bb    = (const float*)d_in[10];
    const float* Wqp   = (const float*)d_in[11];
    const float* bqp   = (const float*)d_in[12];
    const float* Wkvp  = (const float*)d_in[13];
    const float* bkvp  = (const float*)d_in[14];
    const float* gamma = (const float*)d_in[15];
    const float* Wout  = (const float*)d_in[16];
    const float* bout  = (const float*)d_in[17];

    // workspace layout (floats)
    float* ws  = (float*)d_ws;
    float* qw  = ws;
    float* kw  = qw  + (size_t)B * N * HC;
    float* vw  = kw  + (size_t)B * N * HC;
    float* qpw = vw  + (size_t)B * N * HC;
    float* kpxp= qpw + (size_t)B * N * QP3;
    float* vpw = kpxp+ (size_t)B * N * KPX;
    float* feat = vpw + (size_t)B * N * VP3;

    dim3 blk(256);
    hipLaunchKernelGGL(k_proj, dim3(B * N), blk, 0, stream,
                       s, rot, trans, Wq, bq, Wkv, bkv, Wqp, bqp, Wkvp, bkvp,
                       qw, kw, vw, qpw, kpxp, vpw);
    hipLaunchKernelGGL(k_attn, dim3(B * N), blk, 0, stream,
                       z, rot, trans, mask, Wb, bb, gamma,
                       qw, kw, vw, qpw, kpxp, vpw, feat);
    hipLaunchKernelGGL(k_out, dim3(192), blk, 0, stream,
                       feat, Wout, bout, (float*)d_out);
}